// Round 1
// baseline (443.530 us; speedup 1.0000x reference)
//
#include <hip/hip_runtime.h>
#include <hip/hip_bf16.h>
#include <type_traits>

// ---------------------------------------------------------------------------
// CausalSelfAttention: x[4,2048,1024] f32, w_qkv[3072,1024], w_out[1024,1024]
// Pipeline: cvt(bf16) -> GEMM qkv -> causal flash attn -> GEMM out (f32)
// ---------------------------------------------------------------------------

typedef __attribute__((ext_vector_type(8))) short bf16x8;
typedef __attribute__((ext_vector_type(4))) float f32x4;

#define LDS_AS(p) ((__attribute__((address_space(3))) void*)(p))
#define GLB_AS(p) ((const __attribute__((address_space(1))) void*)(p))

// ----------------------------- fp32 -> bf16 --------------------------------
__global__ __launch_bounds__(256) void cvt_f32_bf16(const float* __restrict__ in,
                                                    __hip_bfloat16* __restrict__ out,
                                                    int n4) {
  int i = blockIdx.x * 256 + threadIdx.x;
  if (i >= n4) return;
  float4 v = reinterpret_cast<const float4*>(in)[i];
  __hip_bfloat16 b0 = __float2bfloat16(v.x);
  __hip_bfloat16 b1 = __float2bfloat16(v.y);
  __hip_bfloat16 b2 = __float2bfloat16(v.z);
  __hip_bfloat16 b3 = __float2bfloat16(v.w);
  ushort4 u;
  u.x = *reinterpret_cast<unsigned short*>(&b0);
  u.y = *reinterpret_cast<unsigned short*>(&b1);
  u.z = *reinterpret_cast<unsigned short*>(&b2);
  u.w = *reinterpret_cast<unsigned short*>(&b3);
  reinterpret_cast<ushort4*>(out)[i] = u;
}

// --------------------- GEMM: C[M,N] = A[M,K] * B[N,K]^T --------------------
// m97 structure: 128x128 tile, BK=64, 4 waves (each 64x64), global_load_lds
// width 16, linear LDS, 2 barriers per K-step. M%128==0, N%128==0, K%64==0.
template <typename TOUT>
__global__ __launch_bounds__(256) void gemm_bt(const __hip_bfloat16* __restrict__ A,
                                               const __hip_bfloat16* __restrict__ B,
                                               TOUT* __restrict__ C,
                                               int M, int N, int K) {
  __shared__ __hip_bfloat16 As[128 * 64];
  __shared__ __hip_bfloat16 Bs[128 * 64];
  const int tid = threadIdx.x;
  const int lane = tid & 63;
  const int wid = tid >> 6;
  const int l15 = lane & 15, l4 = lane >> 4;
  const int m0 = blockIdx.x * 128, n0 = blockIdx.y * 128;
  const int wr = (wid >> 1) * 64;  // wave row offset in tile
  const int wc = (wid & 1) * 64;   // wave col offset in tile
  f32x4 acc[4][4] = {};

  for (int kt = 0; kt < K; kt += 64) {
#pragma unroll
    for (int i = 0; i < 4; ++i) {
      const int slot = i * 256 + tid;          // 1024 16B-slots per 128x64 tile
      const int row = slot >> 3, c8 = slot & 7;
      __builtin_amdgcn_global_load_lds(GLB_AS(A + (size_t)(m0 + row) * K + kt + c8 * 8),
                                       LDS_AS((char*)As + slot * 16), 16, 0, 0);
      __builtin_amdgcn_global_load_lds(GLB_AS(B + (size_t)(n0 + row) * K + kt + c8 * 8),
                                       LDS_AS((char*)Bs + slot * 16), 16, 0, 0);
    }
    __syncthreads();
#pragma unroll
    for (int kk = 0; kk < 2; ++kk) {
      bf16x8 af[4], bfr[4];
#pragma unroll
      for (int mi = 0; mi < 4; ++mi)
        af[mi] = *reinterpret_cast<const bf16x8*>(As + (wr + mi * 16 + l15) * 64 + kk * 32 + l4 * 8);
#pragma unroll
      for (int ni = 0; ni < 4; ++ni)
        bfr[ni] = *reinterpret_cast<const bf16x8*>(Bs + (wc + ni * 16 + l15) * 64 + kk * 32 + l4 * 8);
#pragma unroll
      for (int mi = 0; mi < 4; ++mi)
#pragma unroll
        for (int ni = 0; ni < 4; ++ni)
          acc[mi][ni] = __builtin_amdgcn_mfma_f32_16x16x32_bf16(af[mi], bfr[ni], acc[mi][ni], 0, 0, 0);
    }
    __syncthreads();
  }
  // C/D layout (verified m89): row = (lane>>4)*4 + reg, col = lane&15
#pragma unroll
  for (int mi = 0; mi < 4; ++mi)
#pragma unroll
    for (int ni = 0; ni < 4; ++ni)
#pragma unroll
      for (int j = 0; j < 4; ++j) {
        const int m = m0 + wr + mi * 16 + l4 * 4 + j;
        const int n = n0 + wc + ni * 16 + l15;
        if constexpr (std::is_same<TOUT, float>::value)
          C[(size_t)m * N + n] = acc[mi][ni][j];
        else
          C[(size_t)m * N + n] = __float2bfloat16(acc[mi][ni][j]);
      }
}

// --------------------------- causal flash attn -----------------------------
// grid (T/64, H, B), 256 threads. Wave w handles 16 q-rows.
// qkv: [B*T, 3072] bf16 (q at col h*64, k at 1024+h*64, v at 2048+h*64)
// o:   [B*T, 1024] bf16 attention output (pre out-proj)
__global__ __launch_bounds__(256) void attn_causal(const __hip_bfloat16* __restrict__ qkv,
                                                   __hip_bfloat16* __restrict__ o) {
  constexpr int T = 2048, F = 3072, C = 1024;
  __shared__ __hip_bfloat16 Ks[64 * 72];       // K tile  [kv][d], padded
  __shared__ __hip_bfloat16 Vts[64 * 72];      // V tile transposed [d][kv], padded
  __shared__ __hip_bfloat16 Ps[4][16 * 72];    // per-wave P tile [q][kv], padded
  const int tid = threadIdx.x;
  const int wid = tid >> 6, lane = tid & 63;
  const int l15 = lane & 15, l4 = lane >> 4;
  const int qb = blockIdx.x, h = blockIdx.y, b = blockIdx.z;
  const __hip_bfloat16* base = qkv + (size_t)b * T * F;
  const int q0 = qb * 64;
  const int qw = q0 + wid * 16;  // this wave's first q row

  // Q fragments (A operand), held for the whole kernel
  bf16x8 aq[2];
#pragma unroll
  for (int kk = 0; kk < 2; ++kk)
    aq[kk] = *reinterpret_cast<const bf16x8*>(base + (size_t)(qw + l15) * F + h * 64 + kk * 32 + l4 * 8);

  f32x4 acc[4] = {};
  float mrun[4], lrun[4];
#pragma unroll
  for (int j = 0; j < 4; ++j) { mrun[j] = -1e30f; lrun[j] = 0.f; }
  constexpr float SC = 0.125f * 1.44269504088896f;  // 1/sqrt(64) * log2(e)

  for (int kv = 0; kv <= qb; ++kv) {
    const int k0 = kv * 64;
    // ---- stage K [64][72] and V^T [64][72] ----
#pragma unroll
    for (int i = 0; i < 2; ++i) {
      const int slot = i * 256 + tid;
      const int r = slot >> 3, c8 = slot & 7;
      const size_t rowoff = (size_t)(k0 + r) * F + h * 64 + c8 * 8;
      bf16x8 kvv = *reinterpret_cast<const bf16x8*>(base + rowoff + C);
      *reinterpret_cast<bf16x8*>(&Ks[r * 72 + c8 * 8]) = kvv;
      bf16x8 vv = *reinterpret_cast<const bf16x8*>(base + rowoff + 2 * C);
      const __hip_bfloat16* vp = reinterpret_cast<const __hip_bfloat16*>(&vv);
#pragma unroll
      for (int jj = 0; jj < 8; ++jj)
        Vts[(c8 * 8 + jj) * 72 + r] = vp[jj];
    }
    __syncthreads();

    // ---- S = Q K^T (scaled into log2 domain) ----
    f32x4 s[4];
#pragma unroll
    for (int kt = 0; kt < 4; ++kt) {
      f32x4 z = {};
      bf16x8 b0 = *reinterpret_cast<const bf16x8*>(Ks + (kt * 16 + l15) * 72 + l4 * 8);
      bf16x8 b1 = *reinterpret_cast<const bf16x8*>(Ks + (kt * 16 + l15) * 72 + 32 + l4 * 8);
      z = __builtin_amdgcn_mfma_f32_16x16x32_bf16(aq[0], b0, z, 0, 0, 0);
      z = __builtin_amdgcn_mfma_f32_16x16x32_bf16(aq[1], b1, z, 0, 0, 0);
      s[kt] = z;
    }

    // ---- causal mask + online softmax (per q-row = (l4*4+j)) ----
    float mt[4];
#pragma unroll
    for (int j = 0; j < 4; ++j) {
      const int qg = qw + l4 * 4 + j;
#pragma unroll
      for (int kt = 0; kt < 4; ++kt) {
        const int kg = k0 + kt * 16 + l15;
        s[kt][j] = (kg <= qg) ? s[kt][j] * SC : -1e30f;
      }
      float m = fmaxf(fmaxf(s[0][j], s[1][j]), fmaxf(s[2][j], s[3][j]));
#pragma unroll
      for (int d = 1; d < 16; d <<= 1) m = fmaxf(m, __shfl_xor(m, d, 64));
      mt[j] = m;
    }
#pragma unroll
    for (int j = 0; j < 4; ++j) {
      const float mnew = fmaxf(mrun[j], mt[j]);
      const float sc = exp2f(mrun[j] - mnew);
      float rs = 0.f;
#pragma unroll
      for (int kt = 0; kt < 4; ++kt) {
        const float p = exp2f(s[kt][j] - mnew);
        s[kt][j] = p;
        rs += p;
      }
#pragma unroll
      for (int d = 1; d < 16; d <<= 1) rs += __shfl_xor(rs, d, 64);
      lrun[j] = lrun[j] * sc + rs;
      mrun[j] = mnew;
#pragma unroll
      for (int di = 0; di < 4; ++di) acc[di][j] *= sc;
    }

    // ---- P (D-layout) -> LDS -> A-layout fragments ----
    __hip_bfloat16* pw = Ps[wid];
#pragma unroll
    for (int kt = 0; kt < 4; ++kt)
#pragma unroll
      for (int j = 0; j < 4; ++j)
        pw[(l4 * 4 + j) * 72 + kt * 16 + l15] = __float2bfloat16(s[kt][j]);
    bf16x8 pa0 = *reinterpret_cast<const bf16x8*>(pw + l15 * 72 + l4 * 8);
    bf16x8 pa1 = *reinterpret_cast<const bf16x8*>(pw + l15 * 72 + 32 + l4 * 8);

    // ---- O += P V ----
#pragma unroll
    for (int di = 0; di < 4; ++di) {
      bf16x8 v0 = *reinterpret_cast<const bf16x8*>(Vts + (di * 16 + l15) * 72 + l4 * 8);
      bf16x8 v1 = *reinterpret_cast<const bf16x8*>(Vts + (di * 16 + l15) * 72 + 32 + l4 * 8);
      acc[di] = __builtin_amdgcn_mfma_f32_16x16x32_bf16(pa0, v0, acc[di], 0, 0, 0);
      acc[di] = __builtin_amdgcn_mfma_f32_16x16x32_bf16(pa1, v1, acc[di], 0, 0, 0);
    }
    __syncthreads();
  }

  // ---- normalize + write ----
#pragma unroll
  for (int j = 0; j < 4; ++j) {
    const float inv = 1.0f / lrun[j];
    const int qg = qw + l4 * 4 + j;
    __hip_bfloat16* op = o + (size_t)(b * T + qg) * C + h * 64 + l15;
#pragma unroll
    for (int di = 0; di < 4; ++di)
      op[di * 16] = __float2bfloat16(acc[di][j] * inv);
  }
}

// ------------------------------- launcher ----------------------------------
extern "C" void kernel_launch(void* const* d_in, const int* in_sizes, int n_in,
                              void* d_out, int out_size, void* d_ws, size_t ws_size,
                              hipStream_t stream) {
  const float* x = (const float*)d_in[0];       // [4,2048,1024]
  const float* w_qkv = (const float*)d_in[1];   // [3072,1024]
  const float* w_out = (const float*)d_in[2];   // [1024,1024]
  float* out = (float*)d_out;                   // [4,2048,1024] f32

  constexpr int B = 4, T = 2048, C = 1024, F = 3 * C;
  constexpr int M = B * T;  // 8192

  __hip_bfloat16* xb = (__hip_bfloat16*)d_ws;            // M*C
  __hip_bfloat16* wqkvb = xb + (size_t)M * C;            // F*C
  __hip_bfloat16* woutb = wqkvb + (size_t)F * C;         // C*C
  __hip_bfloat16* qkvb = woutb + (size_t)C * C;          // M*F
  __hip_bfloat16* attnb = qkvb + (size_t)M * F;          // M*C

  cvt_f32_bf16<<<(M * C / 4 + 255) / 256, 256, 0, stream>>>(x, xb, M * C / 4);
  cvt_f32_bf16<<<(F * C / 4 + 255) / 256, 256, 0, stream>>>(w_qkv, wqkvb, F * C / 4);
  cvt_f32_bf16<<<(C * C / 4 + 255) / 256, 256, 0, stream>>>(w_out, woutb, C * C / 4);

  gemm_bt<__hip_bfloat16><<<dim3(M / 128, F / 128), 256, 0, stream>>>(xb, wqkvb, qkvb, M, F, C);

  attn_causal<<<dim3(T / 64, 16, B), 256, 0, stream>>>(qkvb, attnb);

  gemm_bt<float><<<dim3(M / 128, C / 128), 256, 0, stream>>>(attnb, woutb, out, M, C, C);
}